// Round 6
// baseline (46.983 us; speedup 1.0000x reference)
//
#include <hip/hip_runtime.h>

#define B_  4
#define NQ_ 256
#define NK_ 512
#define H_  256

// tanh(x) = 1 - 2/(exp2(x*2*log2e)+1), clamped strictly inside (-1,1) so the
// tanh-addition denominator 1+ta*tb is always > 0.
#define TWO_LOG2E 2.8853900817779268f
__device__ __forceinline__ float tanh_fast(float x) {
    float t = __builtin_amdgcn_exp2f(x * TWO_LOG2E);
    float r = __builtin_amdgcn_rcpf(t + 1.0f);
    float y = fmaf(-2.0f, r, 1.0f);
    return fminf(fmaxf(y, -0.99999994f), 0.99999994f);
}

// Both GEMMs, 32x64 tiles, 256 threads, 8 outputs/thread (4m x 2n).
// blocks [0,256):  kt[b][o][k] -> ktTan[b][o>>2][k][o&3] = tanh(kt)
// blocks [256,384): qt[b][q][o] -> tbT = tanh(qt), wbT = v[o]*tanh(qt)
__global__ __launch_bounds__(256)
void gemm_fused(const float* __restrict__ xq, const float* __restrict__ xk,
                const float* __restrict__ w1, const float* __restrict__ w2,
                const float* __restrict__ v,
                float* __restrict__ ktTan,   // [B][H/4][NK][4]
                float* __restrict__ tbT,     // [B][NQ][H]
                float* __restrict__ wbT)     // [B][NQ][H]
{
    constexpr int BK = 32;
    const float* A; const float* Bm;
    int m0, n0, bz; bool iskt;
    {
        int id = blockIdx.x;
        if (id < 256) {                      // kt: M=H(o), N=NK(k)
            iskt = true;
            bz = id >> 6; int t = id & 63;
            m0 = (t >> 3) * 32; n0 = (t & 7) * 64;
            A = w1; Bm = xk + (long)bz * NK_ * H_;
        } else {                             // qt: M=NQ(q), N=H(o)
            iskt = false;
            id -= 256;
            bz = id >> 5; int t = id & 31;
            m0 = (t >> 2) * 32; n0 = (t & 3) * 64;
            A = xq + (long)bz * NQ_ * H_; Bm = w2;
        }
    }
    const int lda = H_, ldb = H_;

    __shared__ float As[BK][36];
    __shared__ float Bs[BK][68];

    const int tid  = threadIdx.x;
    const int arow = tid >> 3, ak = (tid & 7) * 4;
    const int brow = tid >> 2, bk = (tid & 3) * 8;
    const int tm = (tid >> 5) * 4;       // 0..28
    const int tn = (tid & 31) * 2;       // 0..62

    float acc[4][2] = {};

    for (int kt = 0; kt < H_; kt += BK) {
        float4 a0 = *(const float4*)&A [(long)(m0 + arow) * lda + kt + ak];
        float4 b0 = *(const float4*)&Bm[(long)(n0 + brow) * ldb + kt + bk];
        float4 b1 = *(const float4*)&Bm[(long)(n0 + brow) * ldb + kt + bk + 4];
        __syncthreads();
        As[ak+0][arow]=a0.x; As[ak+1][arow]=a0.y; As[ak+2][arow]=a0.z; As[ak+3][arow]=a0.w;
        Bs[bk+0][brow]=b0.x; Bs[bk+1][brow]=b0.y; Bs[bk+2][brow]=b0.z; Bs[bk+3][brow]=b0.w;
        Bs[bk+4][brow]=b1.x; Bs[bk+5][brow]=b1.y; Bs[bk+6][brow]=b1.z; Bs[bk+7][brow]=b1.w;
        __syncthreads();
        #pragma unroll
        for (int kk = 0; kk < BK; ++kk) {
            float4 av = *(const float4*)&As[kk][tm];
            float2 bv = *(const float2*)&Bs[kk][tn];
            float am[4] = {av.x, av.y, av.z, av.w};
            #pragma unroll
            for (int i = 0; i < 4; ++i) {
                acc[i][0] = fmaf(am[i], bv.x, acc[i][0]);
                acc[i][1] = fmaf(am[i], bv.y, acc[i][1]);
            }
        }
    }

    if (iskt) {
        float* cb = ktTan + (long)bz * H_ * NK_ + (long)((m0 + tm) >> 2) * (NK_ * 4);
        #pragma unroll
        for (int j = 0; j < 2; ++j) {
            float4 t4 = { tanh_fast(acc[0][j]), tanh_fast(acc[1][j]),
                          tanh_fast(acc[2][j]), tanh_fast(acc[3][j]) };
            *(float4*)&cb[(n0 + tn + j) * 4] = t4;
        }
    } else {
        float2 v2 = *(const float2*)&v[n0 + tn];
        #pragma unroll
        for (int i = 0; i < 4; ++i) {
            float2 t2 = { tanh_fast(acc[i][0]), tanh_fast(acc[i][1]) };
            float2 w2v = { v2.x * t2.x, v2.y * t2.y };
            long off = ((long)bz * NQ_ + m0 + tm + i) * H_ + n0 + tn;
            *(float2*)&tbT[off] = t2;
            *(float2*)&wbT[off] = w2v;
        }
    }
}

// One block per (b, 2 q-rows), 512 threads = one per k. Uniform q-side
// operands (tb0,tb1,wb0,wb1,v) staged in LDS once, read as ds_read_b128
// broadcasts in the loop -- replaces the s_load latency chain that was
// stalling rounds 3-5. kv is the single per-iter global (L2) access.
__global__ __launch_bounds__(512)
void attn_main(const float4* __restrict__ kt4,  // [B][H/4][NK] float4s
               const float4* __restrict__ tbT,  // [B][NQ][H/4]
               const float4* __restrict__ wbT,
               const float4* __restrict__ v4p,  // [H/4]
               float* __restrict__ out)         // [B][NQ][NK]
{
    const int k = threadIdx.x, b = blockIdx.y, q0 = blockIdx.x * 2;

    __shared__ float4 sQ[5 * 64];   // [t0|t1|w0|w1|v] x 64 float4s = 5 KB
    if (k < 320) {
        const int grp = k >> 6, idx = k & 63;
        const long base = ((long)b * NQ_ + q0) * (H_ / 4);
        const float4* src;
        if      (grp == 0) src = tbT + base;
        else if (grp == 1) src = tbT + base + H_ / 4;
        else if (grp == 2) src = wbT + base;
        else if (grp == 3) src = wbT + base + H_ / 4;
        else               src = v4p;
        sQ[grp * 64 + idx] = src[idx];
    }
    __syncthreads();

    const float4* kp = kt4 + (long)b * (H_ / 4) * NK_ + k;

    float a00 = 0.f, a01 = 0.f, a10 = 0.f, a11 = 0.f;
    #pragma unroll 4
    for (int hc = 0; hc < H_ / 4; ++hc) {
        float4 ta = kp[(long)hc * NK_];
        float4 t0 = sQ[hc],       t1 = sQ[64 + hc];
        float4 w0 = sQ[128 + hc], w1 = sQ[192 + hc];
        float4 vv = sQ[256 + hc];

        a00 = fmaf(fmaf(vv.x, ta.x, w0.x), __builtin_amdgcn_rcpf(fmaf(ta.x, t0.x, 1.f)), a00);
        a10 = fmaf(fmaf(vv.x, ta.x, w1.x), __builtin_amdgcn_rcpf(fmaf(ta.x, t1.x, 1.f)), a10);
        a01 = fmaf(fmaf(vv.y, ta.y, w0.y), __builtin_amdgcn_rcpf(fmaf(ta.y, t0.y, 1.f)), a01);
        a11 = fmaf(fmaf(vv.y, ta.y, w1.y), __builtin_amdgcn_rcpf(fmaf(ta.y, t1.y, 1.f)), a11);
        a00 = fmaf(fmaf(vv.z, ta.z, w0.z), __builtin_amdgcn_rcpf(fmaf(ta.z, t0.z, 1.f)), a00);
        a10 = fmaf(fmaf(vv.z, ta.z, w1.z), __builtin_amdgcn_rcpf(fmaf(ta.z, t1.z, 1.f)), a10);
        a01 = fmaf(fmaf(vv.w, ta.w, w0.w), __builtin_amdgcn_rcpf(fmaf(ta.w, t0.w, 1.f)), a01);
        a11 = fmaf(fmaf(vv.w, ta.w, w1.w), __builtin_amdgcn_rcpf(fmaf(ta.w, t1.w, 1.f)), a11);
    }
    float val[2] = { a00 + a01, a10 + a11 };

    // ---- log-softmax over k (512 threads = 8 waves), 2 rows ----
    __shared__ float red[8][2];
    const int lane = k & 63, wv = k >> 6;
    float m[2], s[2];

    #pragma unroll
    for (int j = 0; j < 2; ++j) {
        float x = val[j];
        #pragma unroll
        for (int o = 32; o; o >>= 1) x = fmaxf(x, __shfl_xor(x, o, 64));
        if (lane == 0) red[wv][j] = x;
    }
    __syncthreads();
    #pragma unroll
    for (int j = 0; j < 2; ++j) {
        float x = red[0][j];
        #pragma unroll
        for (int w = 1; w < 8; ++w) x = fmaxf(x, red[w][j]);
        m[j] = x;
    }
    __syncthreads();
    #pragma unroll
    for (int j = 0; j < 2; ++j) {
        float e = __builtin_amdgcn_exp2f((val[j] - m[j]) * 1.4426950408889634f);
        #pragma unroll
        for (int o = 32; o; o >>= 1) e += __shfl_xor(e, o, 64);
        if (lane == 0) red[wv][j] = e;
    }
    __syncthreads();
    #pragma unroll
    for (int j = 0; j < 2; ++j) {
        float ssum = 0.f;
        #pragma unroll
        for (int w = 0; w < 8; ++w) ssum += red[w][j];
        s[j] = ssum;
    }
    #pragma unroll
    for (int j = 0; j < 2; ++j) {
        float l = __builtin_amdgcn_logf(s[j]) * 0.6931471805599453f;  // ln(s)
        out[((long)b * NQ_ + q0 + j) * NK_ + k] = val[j] - m[j] - l;
    }
}

extern "C" void kernel_launch(void* const* d_in, const int* in_sizes, int n_in,
                              void* d_out, int out_size, void* d_ws, size_t ws_size,
                              hipStream_t stream)
{
    const float* xq = (const float*)d_in[0];  // (4,256,256)
    const float* xk = (const float*)d_in[1];  // (4,512,256)
    const float* w1 = (const float*)d_in[2];  // (256,256) out,in
    const float* w2 = (const float*)d_in[3];  // (256,256)
    const float* v  = (const float*)d_in[4];  // (1,256)
    float* out = (float*)d_out;

    float* ktTan = (float*)d_ws;                          // [4][64][512][4] = 2 MB
    float* tbT   = ktTan + (size_t)B_ * H_ * NK_;         // [4][256][256]   = 1 MB
    float* wbT   = tbT   + (size_t)B_ * NQ_ * H_;         // [4][256][256]   = 1 MB

    gemm_fused<<<dim3(384), 256, 0, stream>>>(xq, xk, w1, w2, v, ktTan, tbT, wbT);
    attn_main<<<dim3(NQ_ / 2, B_), 512, 0, stream>>>(
        (const float4*)ktTan, (const float4*)tbT, (const float4*)wbT,
        (const float4*)v, out);
}

// Round 7
// 42.904 us; speedup vs baseline: 1.0951x; 1.0951x over previous
//
#include <hip/hip_runtime.h>

#define B_  4
#define NQ_ 256
#define NK_ 512
#define H_  256

// tanh(x) = 1 - 2/(exp2(x*2*log2e)+1), clamped strictly inside (-1,1) so the
// tanh-addition denominator 1+ta*tb is always > 0.
#define TWO_LOG2E 2.8853900817779268f
__device__ __forceinline__ float tanh_fast(float x) {
    float t = __builtin_amdgcn_exp2f(x * TWO_LOG2E);
    float r = __builtin_amdgcn_rcpf(t + 1.0f);
    float y = fmaf(-2.0f, r, 1.0f);
    return fminf(fmaxf(y, -0.99999994f), 0.99999994f);
}

// Both GEMMs, 32x64 tiles, 256 threads, 8 outputs/thread (4m x 2n).
// Register-double-buffered global->LDS pipeline: load(i+1) overlaps compute(i).
// blocks [0,256):  kt[b][o][k] -> ktTan[b][o>>2][k][o&3] = tanh(kt)
// blocks [256,384): qt[b][q][o] -> tbT = tanh(qt), wbT = v[o]*tanh(qt)
__global__ __launch_bounds__(256)
void gemm_fused(const float* __restrict__ xq, const float* __restrict__ xk,
                const float* __restrict__ w1, const float* __restrict__ w2,
                const float* __restrict__ v,
                float* __restrict__ ktTan,   // [B][H/4][NK][4]
                float* __restrict__ tbT,     // [B][NQ][H]
                float* __restrict__ wbT)     // [B][NQ][H]
{
    constexpr int BK = 32;
    const float* A; const float* Bm;
    int m0, n0, bz; bool iskt;
    {
        int id = blockIdx.x;
        if (id < 256) {                      // kt: M=H(o), N=NK(k)
            iskt = true;
            bz = id >> 6; int t = id & 63;
            m0 = (t >> 3) * 32; n0 = (t & 7) * 64;
            A = w1; Bm = xk + (long)bz * NK_ * H_;
        } else {                             // qt: M=NQ(q), N=H(o)
            iskt = false;
            id -= 256;
            bz = id >> 5; int t = id & 31;
            m0 = (t >> 2) * 32; n0 = (t & 3) * 64;
            A = xq + (long)bz * NQ_ * H_; Bm = w2;
        }
    }
    const int lda = H_, ldb = H_;

    __shared__ float As[BK][36];
    __shared__ float Bs[BK][68];

    const int tid  = threadIdx.x;
    const int arow = tid >> 3, ak = (tid & 7) * 4;
    const int brow = tid >> 2, bk = (tid & 3) * 8;
    const int tm = (tid >> 5) * 4;       // 0..28
    const int tn = (tid & 31) * 2;       // 0..62

    float acc[4][2] = {};

    // prologue: issue loads for tile 0
    float4 a_r  = *(const float4*)&A [(long)(m0 + arow) * lda + ak];
    float4 b0_r = *(const float4*)&Bm[(long)(n0 + brow) * ldb + bk];
    float4 b1_r = *(const float4*)&Bm[(long)(n0 + brow) * ldb + bk + 4];
    float4 a_n, b0_n, b1_n;

    for (int kt = 0; kt < H_; kt += BK) {
        __syncthreads();   // previous iteration's readers done
        As[ak+0][arow]=a_r.x; As[ak+1][arow]=a_r.y; As[ak+2][arow]=a_r.z; As[ak+3][arow]=a_r.w;
        Bs[bk+0][brow]=b0_r.x; Bs[bk+1][brow]=b0_r.y; Bs[bk+2][brow]=b0_r.z; Bs[bk+3][brow]=b0_r.w;
        Bs[bk+4][brow]=b1_r.x; Bs[bk+5][brow]=b1_r.y; Bs[bk+6][brow]=b1_r.z; Bs[bk+7][brow]=b1_r.w;
        if (kt + BK < H_) {   // issue next-tile loads; latency hides under compute
            a_n  = *(const float4*)&A [(long)(m0 + arow) * lda + kt + BK + ak];
            b0_n = *(const float4*)&Bm[(long)(n0 + brow) * ldb + kt + BK + bk];
            b1_n = *(const float4*)&Bm[(long)(n0 + brow) * ldb + kt + BK + bk + 4];
        }
        __syncthreads();
        #pragma unroll
        for (int kk = 0; kk < BK; ++kk) {
            float4 av = *(const float4*)&As[kk][tm];
            float2 bv = *(const float2*)&Bs[kk][tn];
            float am[4] = {av.x, av.y, av.z, av.w};
            #pragma unroll
            for (int i = 0; i < 4; ++i) {
                acc[i][0] = fmaf(am[i], bv.x, acc[i][0]);
                acc[i][1] = fmaf(am[i], bv.y, acc[i][1]);
            }
        }
        a_r = a_n; b0_r = b0_n; b1_r = b1_n;
    }

    if (iskt) {
        float* cb = ktTan + (long)bz * H_ * NK_ + (long)((m0 + tm) >> 2) * (NK_ * 4);
        #pragma unroll
        for (int j = 0; j < 2; ++j) {
            float4 t4 = { tanh_fast(acc[0][j]), tanh_fast(acc[1][j]),
                          tanh_fast(acc[2][j]), tanh_fast(acc[3][j]) };
            *(float4*)&cb[(n0 + tn + j) * 4] = t4;
        }
    } else {
        float2 v2 = *(const float2*)&v[n0 + tn];
        #pragma unroll
        for (int i = 0; i < 4; ++i) {
            float2 t2 = { tanh_fast(acc[i][0]), tanh_fast(acc[i][1]) };
            float2 w2v = { v2.x * t2.x, v2.y * t2.y };
            long off = ((long)bz * NQ_ + m0 + tm + i) * H_ + n0 + tn;
            *(float2*)&tbT[off] = t2;
            *(float2*)&wbT[off] = w2v;
        }
    }
}

// One block per (b, 2 q-rows), 512 threads = one per k.
// prod = sum_h p/d with p=fma(v,ta,wb), d=fma(ta,tb,1). Four terms combined
// over a common denominator -> ONE v_rcp per 4 elements (trans pipe is the
// bottleneck at ~16 cyc/wave64-rcp). log-softmax without max-pass (|val|<=16
// so exp is fp32-safe; algebraically identical).
__global__ __launch_bounds__(512)
void attn_main(const float4* __restrict__ kt4,  // [B][H/4][NK] float4s
               const float4* __restrict__ tbT,  // [B][NQ][H/4]
               const float4* __restrict__ wbT,
               const float4* __restrict__ v4p,  // [H/4]
               float* __restrict__ out)         // [B][NQ][NK]
{
    const int k = threadIdx.x, b = blockIdx.y, q0 = blockIdx.x * 2;
    const float4* kp  = kt4 + (long)b * (H_ / 4) * NK_ + k;
    const float4* t0p = tbT + ((long)b * NQ_ + q0) * (H_ / 4);
    const float4* w0p = wbT + ((long)b * NQ_ + q0) * (H_ / 4);
    const float4* t1p = t0p + (H_ / 4);
    const float4* w1p = w0p + (H_ / 4);

    float acc0 = 0.f, acc1 = 0.f;
    #pragma unroll 2
    for (int hc = 0; hc < H_ / 4; ++hc) {
        float4 ta = kp[(long)hc * NK_];
        float4 vv = v4p[hc];
        float4 t0 = t0p[hc], w0 = w0p[hc];
        float4 t1 = t1p[hc], w1 = w1p[hc];

        {   // q0: 4 terms, 1 rcp
            float d0 = fmaf(ta.x, t0.x, 1.f), d1 = fmaf(ta.y, t0.y, 1.f);
            float d2 = fmaf(ta.z, t0.z, 1.f), d3 = fmaf(ta.w, t0.w, 1.f);
            float p0 = fmaf(vv.x, ta.x, w0.x), p1 = fmaf(vv.y, ta.y, w0.y);
            float p2 = fmaf(vv.z, ta.z, w0.z), p3 = fmaf(vv.w, ta.w, w0.w);
            float D01 = d0 * d1, D23 = d2 * d3;
            float N01 = fmaf(p0, d1, p1 * d0);
            float N23 = fmaf(p2, d3, p3 * d2);
            float N   = fmaf(N01, D23, N23 * D01);
            acc0 = fmaf(N, __builtin_amdgcn_rcpf(D01 * D23), acc0);
        }
        {   // q1
            float d0 = fmaf(ta.x, t1.x, 1.f), d1 = fmaf(ta.y, t1.y, 1.f);
            float d2 = fmaf(ta.z, t1.z, 1.f), d3 = fmaf(ta.w, t1.w, 1.f);
            float p0 = fmaf(vv.x, ta.x, w1.x), p1 = fmaf(vv.y, ta.y, w1.y);
            float p2 = fmaf(vv.z, ta.z, w1.z), p3 = fmaf(vv.w, ta.w, w1.w);
            float D01 = d0 * d1, D23 = d2 * d3;
            float N01 = fmaf(p0, d1, p1 * d0);
            float N23 = fmaf(p2, d3, p3 * d2);
            float N   = fmaf(N01, D23, N23 * D01);
            acc1 = fmaf(N, __builtin_amdgcn_rcpf(D01 * D23), acc1);
        }
    }

    // ---- log-softmax over k, no max pass ----
    __shared__ float red[8][2];
    const int lane = k & 63, wv = k >> 6;

    float e0 = __builtin_amdgcn_exp2f(acc0 * 1.4426950408889634f);
    float e1 = __builtin_amdgcn_exp2f(acc1 * 1.4426950408889634f);
    #pragma unroll
    for (int o = 32; o; o >>= 1) {
        e0 += __shfl_xor(e0, o, 64);
        e1 += __shfl_xor(e1, o, 64);
    }
    if (lane == 0) { red[wv][0] = e0; red[wv][1] = e1; }
    __syncthreads();
    float s0 = 0.f, s1 = 0.f;
    #pragma unroll
    for (int w = 0; w < 8; ++w) { s0 += red[w][0]; s1 += red[w][1]; }

    float l0 = __builtin_amdgcn_logf(s0) * 0.6931471805599453f;  // ln(s0)
    float l1 = __builtin_amdgcn_logf(s1) * 0.6931471805599453f;
    out[((long)b * NQ_ + q0 + 0) * NK_ + k] = acc0 - l0;
    out[((long)b * NQ_ + q0 + 1) * NK_ + k] = acc1 - l1;
}

extern "C" void kernel_launch(void* const* d_in, const int* in_sizes, int n_in,
                              void* d_out, int out_size, void* d_ws, size_t ws_size,
                              hipStream_t stream)
{
    const float* xq = (const float*)d_in[0];  // (4,256,256)
    const float* xk = (const float*)d_in[1];  // (4,512,256)
    const float* w1 = (const float*)d_in[2];  // (256,256) out,in
    const float* w2 = (const float*)d_in[3];  // (256,256)
    const float* v  = (const float*)d_in[4];  // (1,256)
    float* out = (float*)d_out;

    float* ktTan = (float*)d_ws;                          // [4][64][512][4] = 2 MB
    float* tbT   = ktTan + (size_t)B_ * H_ * NK_;         // [4][256][256]   = 1 MB
    float* wbT   = tbT   + (size_t)B_ * NQ_ * H_;         // [4][256][256]   = 1 MB

    gemm_fused<<<dim3(384), 256, 0, stream>>>(xq, xk, w1, w2, v, ktTan, tbT, wbT);
    attn_main<<<dim3(NQ_ / 2, B_), 512, 0, stream>>>(
        (const float4*)ktTan, (const float4*)tbT, (const float4*)wbT,
        (const float4*)v, out);
}